// Round 17
// baseline (34.110 us; speedup 1.0000x reference)
//
#include <hip/hip_runtime.h>
#include <hip/hip_bf16.h>
#include <cstdint>

#define NN 8192
#define DD 512
#define NC 128      // number of classes

typedef unsigned short u16;
typedef __attribute__((ext_vector_type(8))) short short8;
typedef __attribute__((ext_vector_type(4))) float f32x4;

#define AS1 __attribute__((address_space(1)))
#define AS3 __attribute__((address_space(3)))

__device__ __forceinline__ float bf2f(short x) {
  return __uint_as_float(((unsigned)(unsigned short)x) << 16);
}

// workspace layout (bytes)
#define FB_OFF   ((size_t)0)                      // bf16 features: NN*DD*2 = 8 MB
#define SQ_OFF   (FB_OFF + (size_t)NN*DD*2)       // fp32 sq norms: NN*4
#define ACC_OFF  (SQ_OFF + (size_t)NN*4)          // total(f32)@+0, cnt(int)@+4, done(int)@+8
#define CC_OFF   (ACC_OFF + 64)                   // class counts: NC*4
#define POS_OFF  (CC_OFF + 1024)                  // ordered member positions: NC*128*4

// ---- K1: fused {sq norms + bf16 cast + acc zero} | {per-class positions} --
// blocks 0..2047: prep (reads F only; writes Fb, sq). block 0 zeroes the
// accumulator line (NO atomics anywhere in this kernel -> plain stores
// flushed at kernel end, before k_cls's atomics — r9-verified pattern).
// blocks 2048..2175: classpos (reads labels only; writes cc, pos).
__global__ __launch_bounds__(256) void k_pc(const float* __restrict__ F,
    const int* __restrict__ labels, u16* __restrict__ Fb,
    float* __restrict__ sq, int* __restrict__ cc, int* __restrict__ pos,
    int* __restrict__ accz) {
  const int wid = threadIdx.x >> 6, lane = threadIdx.x & 63;
  if (blockIdx.x < 2048) {               // ---------------- prep half
    if (blockIdx.x == 0 && threadIdx.x < 16) accz[threadIdx.x] = 0;
    const int row = blockIdx.x * 4 + wid;
    const float* fr = F + (size_t)row * DD + lane * 8;
    float4 v0 = *(const float4*)fr;
    float4 v1 = *(const float4*)(fr + 4);
    float s = v0.x*v0.x + v0.y*v0.y + v0.z*v0.z + v0.w*v0.w
            + v1.x*v1.x + v1.y*v1.y + v1.z*v1.z + v1.w*v1.w;
    #pragma unroll
    for (int o = 32; o; o >>= 1) s += __shfl_xor(s, o);
    float t[8] = {v0.x, v0.y, v0.z, v0.w, v1.x, v1.y, v1.z, v1.w};
    unsigned p[8];
    #pragma unroll
    for (int e = 0; e < 8; ++e) {   // RNE fp32->bf16
      unsigned b = __float_as_uint(t[e]);
      b += 0x7fffu + ((b >> 16) & 1u);
      p[e] = b >> 16;
    }
    uint4 w;
    w.x = p[0] | (p[1] << 16); w.y = p[2] | (p[3] << 16);
    w.z = p[4] | (p[5] << 16); w.w = p[6] | (p[7] << 16);
    *(uint4*)(Fb + (size_t)row * DD + lane * 8) = w;
    if (lane == 0) sq[row] = s;
  } else {                               // ---------------- classpos half
    const int c = blockIdx.x - 2048;
    __shared__ int wcnt[4], woff[4];
    const int base0 = wid * 2048;
    int cw = 0;
    for (int b = 0; b < 2048; b += 64)   // pass 1: count
      cw += __popcll(__ballot(labels[base0 + b + lane] == c));
    if (lane == 0) wcnt[wid] = cw;
    __syncthreads();
    if (threadIdx.x == 0) {
      int o = 0;
      #pragma unroll
      for (int w = 0; w < 4; ++w) { woff[w] = o; o += wcnt[w]; }
      cc[c] = o;
    }
    __syncthreads();
    int off = woff[wid];
    for (int b = 0; b < 2048; b += 64) { // pass 2: emit (ascending order)
      const int idx = base0 + b + lane;
      const int hit = (labels[idx] == c);
      const unsigned long long m = __ballot(hit);
      if (hit) pos[c * 128 + off + __popcll(m & ((1ull << lane) - 1ull))] = idx;
      off += __popcll(m);
    }
    __syncthreads();
    const int nc = cc[c];
    for (int t = nc + threadIdx.x; t < 128; t += 256) pos[c * 128 + t] = 0;
  }
}

// ---- K2: per-class Gram, ONE block/class, 512 threads (8 waves) ----------
// Stages the 128 KB class tile ONCE (16 MB total vs 32 MB for M-split);
// 2 waves/SIMD give cross-wave overlap of staging drain, nd-dots and MFMA.
// nd: thread = (member, quarter) -> 512 independent bf16 streams issued
// while staging is in flight. All accumulator traffic atomic (r9 pattern).
__global__ __launch_bounds__(512) void k_cls(const u16* __restrict__ Fb,
    const float* __restrict__ sq, const float* __restrict__ negu,
    const int* __restrict__ cc, const int* __restrict__ pos,
    float* __restrict__ accf, float* __restrict__ out) {
  const int c = blockIdx.x;
  __shared__ __align__(16) u16 P[128 * 512];     // 128 KB: full class tile
  __shared__ int posc[128], jm[128];
  __shared__ float pd[128][4], ndc[128], sqc[128];
  __shared__ float red[8];
  const int tid = threadIdx.x, wid = tid >> 6, lane = tid & 63;
  const int nc = cc[c];
  if (tid < 128) posc[tid] = pos[c * 128 + tid];
  __syncthreads();
  if (nc >= 2) {                                 // uniform branch per block
    const int wr = wid >> 2, wc = wid & 3;       // wave grid: 2 x 4
    const int r16 = lane & 15, gg = lane >> 4;
    const char* fb = (const char*)Fb;

    // stage: wave wid covers rows wid*16..wid*16+15; one instr = one row
    // (64 lanes x 16B). lane l -> LDS granule l, global granule l^(row&7).
    #pragma unroll 4
    for (int s = 0; s < 16; ++s) {
      const int row = wid * 16 + s;
      const int gr = posc[row];
      __builtin_amdgcn_global_load_lds(
          (const AS1 void*)(fb + (size_t)gr * 1024 + ((lane ^ (row & 7)) << 4)),
          (AS3 void*)(&P[row * 512]), 16, 0, 0);
    }

    if (tid < 128) sqc[tid] = sq[posc[tid]];     // sq gather -> LDS

    // ---- in-flight nd for all anchors (thread = member, quarter) ----
    // bf16 dot from Fb (same lines staging pulls); fp32 accumulate.
    {
      const int ml = tid >> 2, q = tid & 3;      // 128 members x 4 quarters
      if (ml < nc) {
        const int i = posc[ml];
        const int n_neg = NN - nc;
        int k = (int)floorf(negu[i] * (float)n_neg);  // exact fp32 replica
        k = k < 0 ? 0 : (k > n_neg - 1 ? n_neg - 1 : k);
        int lo = 0, hi = nc;                     // t* = #{t: posc[t]-t <= k}
        while (lo < hi) {
          const int mid = (lo + hi) >> 1;
          if (posc[mid] - mid <= k) lo = mid + 1; else hi = mid;
        }
        const int j = k + lo;
        if (q == 0) jm[ml] = j;
        const u16* fi = Fb + (size_t)i * DD + q * 128;
        const u16* fj = Fb + (size_t)j * DD + q * 128;
        float d = 0.0f;
        #pragma unroll 4
        for (int e = 0; e < 16; ++e) {
          const short8 a = ((const short8*)fi)[e];
          const short8 b = ((const short8*)fj)[e];
          #pragma unroll
          for (int x = 0; x < 8; ++x) d += bf2f(a[x]) * bf2f(b[x]);
        }
        pd[ml][q] = d;
      }
    }

    f32x4 acc[4][2];
    #pragma unroll
    for (int m = 0; m < 4; ++m)
      #pragma unroll
      for (int n = 0; n < 2; ++n)
        #pragma unroll
        for (int q = 0; q < 4; ++q) acc[m][n][q] = 0.0f;

    __syncthreads();                             // staging + pd/jm/sqc done
    if (tid < 128) {                             // finalize ndc (LDS-local)
      if (tid < nc) {
        const float d = pd[tid][0] + pd[tid][1] + pd[tid][2] + pd[tid][3];
        ndc[tid] = sqrtf(fmaxf(sqc[tid] + sq[jm[tid]] - 2.0f * d, 1e-11f));
      } else ndc[tid] = __builtin_inff();
    }

    #pragma unroll 4
    for (int t = 0; t < 16; ++t) {               // K = 16 x 32
      short8 af[4], bf[2];
      #pragma unroll
      for (int m = 0; m < 4; ++m) {
        const int row = wr * 64 + m * 16 + r16;
        const int gl = (t * 4 + gg) ^ (row & 7);
        af[m] = *(const short8*)&P[row * 512 + gl * 8];
      }
      #pragma unroll
      for (int n = 0; n < 2; ++n) {
        const int row = wc * 32 + n * 16 + r16;
        const int gl = (t * 4 + gg) ^ (row & 7);
        bf[n] = *(const short8*)&P[row * 512 + gl * 8];
      }
      #pragma unroll
      for (int m = 0; m < 4; ++m)
        #pragma unroll
        for (int n = 0; n < 2; ++n)
          acc[m][n] = __builtin_amdgcn_mfma_f32_16x16x32_bf16(af[m], bf[n], acc[m][n], 0, 0, 0);
    }
    __syncthreads();                             // ndc visible to all waves

    // epilogue: hinge over valid (mi != nj, both < nc) ordered pairs
    float lsum = 0.0f;
    int njv[2]; float sqj[2];
    #pragma unroll
    for (int n = 0; n < 2; ++n) {
      const int nj = wc * 32 + n * 16 + r16;
      njv[n] = nj; sqj[n] = sqc[nj];
    }
    #pragma unroll
    for (int m = 0; m < 4; ++m) {
      #pragma unroll
      for (int q = 0; q < 4; ++q) {
        const int mi = wr * 64 + m * 16 + gg * 4 + q;   // C/D: row=(lane>>4)*4+q
        const float sqi = sqc[mi];
        const float ndi = ndc[mi];
        const bool vi = mi < nc;
        #pragma unroll
        for (int n = 0; n < 2; ++n) {
          const float g = acc[m][n][q];
          const float dist = sqrtf(fmaxf(sqi + sqj[n] - 2.0f * g, 1e-11f));
          if (vi & (njv[n] < nc) & (mi != njv[n]))
            lsum += fmaxf(1.0f + dist - ndi, 0.0f);     // nd=inf -> 0 automatically
        }
      }
    }
    #pragma unroll
    for (int o = 32; o; o >>= 1) lsum += __shfl_xor(lsum, o);
    if (lane == 0) red[wid] = lsum;
    __syncthreads();
    if (tid == 0) {
      float s = 0.0f;
      #pragma unroll
      for (int w = 0; w < 8; ++w) s += red[w];
      atomicAdd(accf, s);
    }
  }
  // pair-count + last-block finalize (atomics only on this line)
  if (tid == 0) {
    int* cnt  = (int*)accf + 1;
    int* done = (int*)accf + 2;
    if (nc < NN) atomicAdd(cnt, nc * (nc - 1));
    __threadfence();
    if (atomicAdd(done, 1) == NC - 1) {
      const float tot = atomicAdd(accf, 0.0f);    // atomic read
      const int n = atomicAdd(cnt, 0);            // atomic read
      out[0] = tot / (float)n;
    }
  }
}

extern "C" void kernel_launch(void* const* d_in, const int* in_sizes, int n_in,
                              void* d_out, int out_size, void* d_ws, size_t ws_size,
                              hipStream_t stream) {
  const float* F = (const float*)d_in[0];
  const int* labels = (const int*)d_in[1];   // harness materializes integers as int32
  const float* negu = (const float*)d_in[2];
  char* ws = (char*)d_ws;
  u16*   Fb    = (u16*)(ws + FB_OFF);
  float* sq    = (float*)(ws + SQ_OFF);
  float* accf  = (float*)(ws + ACC_OFF);
  int*   cc    = (int*)(ws + CC_OFF);
  int*   pos   = (int*)(ws + POS_OFF);

  k_pc <<<2048 + NC, 256, 0, stream>>>(F, labels, Fb, sq, cc, pos, (int*)accf);
  k_cls<<<NC,        512, 0, stream>>>(Fb, sq, negu, cc, pos, accf, (float*)d_out);
}

// Round 18
// 33.530 us; speedup vs baseline: 1.0173x; 1.0173x over previous
//
#include <hip/hip_runtime.h>
#include <hip/hip_bf16.h>
#include <cstdint>

#define NN 8192
#define DD 512
#define NC 128      // number of classes

typedef unsigned short u16;
typedef __attribute__((ext_vector_type(8))) short short8;
typedef __attribute__((ext_vector_type(4))) float f32x4;

#define AS1 __attribute__((address_space(1)))
#define AS3 __attribute__((address_space(3)))

__device__ __forceinline__ float bf2f(short x) {
  return __uint_as_float(((unsigned)(unsigned short)x) << 16);
}

// workspace layout (bytes)
#define FB_OFF   ((size_t)0)                      // bf16 features: NN*DD*2 = 8 MB
#define SQ_OFF   (FB_OFF + (size_t)NN*DD*2)       // fp32 sq norms: NN*4
#define ACC_OFF  (SQ_OFF + (size_t)NN*4)          // total(f32)@+0, cnt(int)@+4, done(int)@+8
#define CC_OFF   (ACC_OFF + 64)                   // class counts: NC*4
#define POS_OFF  (CC_OFF + 1024)                  // ordered member positions: NC*128*4

// ---- K1: fused {sq norms + bf16 cast + acc zero} | {per-class positions} --
// blocks 0..2047: prep (reads F only; writes Fb, sq). block 0 zeroes the
// accumulator line (NO atomics anywhere in this kernel -> plain stores
// flushed at kernel end, before k_cls's atomics — r9-verified pattern).
// blocks 2048..2175: classpos (reads labels only; writes cc, pos).
__global__ __launch_bounds__(256) void k_pc(const float* __restrict__ F,
    const int* __restrict__ labels, u16* __restrict__ Fb,
    float* __restrict__ sq, int* __restrict__ cc, int* __restrict__ pos,
    int* __restrict__ accz) {
  const int wid = threadIdx.x >> 6, lane = threadIdx.x & 63;
  if (blockIdx.x < 2048) {               // ---------------- prep half
    if (blockIdx.x == 0 && threadIdx.x < 16) accz[threadIdx.x] = 0;
    const int row = blockIdx.x * 4 + wid;
    const float* fr = F + (size_t)row * DD + lane * 8;
    float4 v0 = *(const float4*)fr;
    float4 v1 = *(const float4*)(fr + 4);
    float s = v0.x*v0.x + v0.y*v0.y + v0.z*v0.z + v0.w*v0.w
            + v1.x*v1.x + v1.y*v1.y + v1.z*v1.z + v1.w*v1.w;
    #pragma unroll
    for (int o = 32; o; o >>= 1) s += __shfl_xor(s, o);
    float t[8] = {v0.x, v0.y, v0.z, v0.w, v1.x, v1.y, v1.z, v1.w};
    unsigned p[8];
    #pragma unroll
    for (int e = 0; e < 8; ++e) {   // RNE fp32->bf16
      unsigned b = __float_as_uint(t[e]);
      b += 0x7fffu + ((b >> 16) & 1u);
      p[e] = b >> 16;
    }
    uint4 w;
    w.x = p[0] | (p[1] << 16); w.y = p[2] | (p[3] << 16);
    w.z = p[4] | (p[5] << 16); w.w = p[6] | (p[7] << 16);
    *(uint4*)(Fb + (size_t)row * DD + lane * 8) = w;
    if (lane == 0) sq[row] = s;
  } else {                               // ---------------- classpos half
    const int c = blockIdx.x - 2048;
    __shared__ int wcnt[4], woff[4];
    const int base0 = wid * 2048;
    int cw = 0;
    for (int b = 0; b < 2048; b += 64)   // pass 1: count
      cw += __popcll(__ballot(labels[base0 + b + lane] == c));
    if (lane == 0) wcnt[wid] = cw;
    __syncthreads();
    if (threadIdx.x == 0) {
      int o = 0;
      #pragma unroll
      for (int w = 0; w < 4; ++w) { woff[w] = o; o += wcnt[w]; }
      cc[c] = o;
    }
    __syncthreads();
    int off = woff[wid];
    for (int b = 0; b < 2048; b += 64) { // pass 2: emit (ascending order)
      const int idx = base0 + b + lane;
      const int hit = (labels[idx] == c);
      const unsigned long long m = __ballot(hit);
      if (hit) pos[c * 128 + off + __popcll(m & ((1ull << lane) - 1ull))] = idx;
      off += __popcll(m);
    }
    __syncthreads();
    const int nc = cc[c];
    for (int t = nc + threadIdx.x; t < 128; t += 256) pos[c * 128 + t] = 0;
  }
}

// ---- K2: per-class Gram (M-split) + in-flight bf16 nd + nr-bounded work --
// r16 verbatim EXCEPT: staging and MFMA bounded to nr = ceil(nc/16)*16 rows.
// Un-staged LDS rows are only read by output tiles fully masked by the
// (mi<nc & njv<nc) epilogue guard -> garbage never contributes.
// XCD pairing: c = bid&127, half = bid>>7 (same-XCD L2 reuse of the tile).
__global__ __launch_bounds__(256) void k_cls(const u16* __restrict__ Fb,
    const float* __restrict__ sq, const float* __restrict__ negu,
    const int* __restrict__ cc, const int* __restrict__ pos,
    float* __restrict__ accf, float* __restrict__ out) {
  const int c = blockIdx.x & 127, half = blockIdx.x >> 7;
  __shared__ __align__(16) u16 P[128 * 512];     // 128 KB: full class tile
  __shared__ int posc[128], jm[64];
  __shared__ float pd[64][4], ndc[64], sqc[128];
  __shared__ float red[4];
  const int tid = threadIdx.x, wid = tid >> 6, lane = tid & 63;
  const int nc = cc[c];
  if (tid < 128) posc[tid] = pos[c * 128 + tid];
  __syncthreads();
  if (nc >= 2 && half * 64 < nc) {               // uniform branch per block
    const int nr = (nc + 15) & ~15;              // bounded rows (16..128)
    const int wr = half, wc = wid;               // wave grid: 1 x 4
    const int r16 = lane & 15, gg = lane >> 4;
    const char* fb = (const char*)Fb;

    // stage: wave wid covers rows wid*32..wid*32+31, SKIPPING rows >= nr.
    // lane l -> LDS granule l, global granule l^(s&7).
    #pragma unroll 8
    for (int s = 0; s < 32; ++s) {
      const int row = wid * 32 + s;
      if (row < nr) {
        const int gr = posc[row];
        __builtin_amdgcn_global_load_lds(
            (const AS1 void*)(fb + (size_t)gr * 1024 + ((lane ^ (s & 7)) << 4)),
            (AS3 void*)(&P[row * 512]), 16, 0, 0);
      }
    }

    if (tid < 128) sqc[tid] = sq[posc[tid]];     // sq gather -> LDS

    // ---- in-flight nd for this half's 64 anchors (thread = member,quarter)
    // bf16 dot from Fb (same lines staging pulls); fp32 accumulate.
    {
      const int ml = tid >> 2, q = tid & 3;
      const int row = half * 64 + ml;
      if (row < nc) {
        const int i = posc[row];
        const int n_neg = NN - nc;
        int k = (int)floorf(negu[i] * (float)n_neg);  // exact fp32 replica
        k = k < 0 ? 0 : (k > n_neg - 1 ? n_neg - 1 : k);
        int lo = 0, hi = nc;                     // t* = #{t: posc[t]-t <= k}
        while (lo < hi) {
          const int mid = (lo + hi) >> 1;
          if (posc[mid] - mid <= k) lo = mid + 1; else hi = mid;
        }
        const int j = k + lo;
        if (q == 0) jm[ml] = j;
        const u16* fi = Fb + (size_t)i * DD + q * 128;
        const u16* fj = Fb + (size_t)j * DD + q * 128;
        float d = 0.0f;
        #pragma unroll 4
        for (int e = 0; e < 16; ++e) {
          const short8 a = ((const short8*)fi)[e];
          const short8 b = ((const short8*)fj)[e];
          #pragma unroll
          for (int x = 0; x < 8; ++x) d += bf2f(a[x]) * bf2f(b[x]);
        }
        pd[ml][q] = d;
      }
    }

    f32x4 acc[4][2];
    #pragma unroll
    for (int m = 0; m < 4; ++m)
      #pragma unroll
      for (int n = 0; n < 2; ++n)
        #pragma unroll
        for (int q = 0; q < 4; ++q) acc[m][n][q] = 0.0f;

    __syncthreads();                             // staging + pd/jm/sqc done
    if (tid < 64) {                              // finalize ndc (LDS-local)
      const int row = half * 64 + tid;
      if (row < nc) {
        const float d = pd[tid][0] + pd[tid][1] + pd[tid][2] + pd[tid][3];
        ndc[tid] = sqrtf(fmaxf(sqc[row] + sq[jm[tid]] - 2.0f * d, 1e-11f));
      } else ndc[tid] = __builtin_inff();
    }

    if (wc * 32 < nr) {                          // wave-uniform: stripe live?
      #pragma unroll 4
      for (int t = 0; t < 16; ++t) {             // K = 16 x 32
        short8 af[4], bf[2];
        #pragma unroll
        for (int m = 0; m < 4; ++m) {
          const int row = wr * 64 + m * 16 + r16;
          const int gl = (t * 4 + gg) ^ (row & 7);
          af[m] = *(const short8*)&P[row * 512 + gl * 8];
        }
        #pragma unroll
        for (int n = 0; n < 2; ++n) {
          const int row = wc * 32 + n * 16 + r16;
          const int gl = (t * 4 + gg) ^ (row & 7);
          bf[n] = *(const short8*)&P[row * 512 + gl * 8];
        }
        #pragma unroll
        for (int m = 0; m < 4; ++m)
          #pragma unroll
          for (int n = 0; n < 2; ++n)
            acc[m][n] = __builtin_amdgcn_mfma_f32_16x16x32_bf16(af[m], bf[n], acc[m][n], 0, 0, 0);
      }
    }
    __syncthreads();                             // ndc visible to all waves

    // epilogue: hinge over valid (mi != nj, both < nc) ordered pairs
    float lsum = 0.0f;
    int njv[2]; float sqj[2];
    #pragma unroll
    for (int n = 0; n < 2; ++n) {
      const int nj = wc * 32 + n * 16 + r16;
      njv[n] = nj; sqj[n] = sqc[nj];
    }
    #pragma unroll
    for (int m = 0; m < 4; ++m) {
      #pragma unroll
      for (int q = 0; q < 4; ++q) {
        const int mi = wr * 64 + m * 16 + gg * 4 + q;   // C/D: row=(lane>>4)*4+q
        const float sqi = sqc[mi];
        const float ndi = ndc[mi - half * 64];
        const bool vi = mi < nc;
        #pragma unroll
        for (int n = 0; n < 2; ++n) {
          const float g = acc[m][n][q];
          const float dist = sqrtf(fmaxf(sqi + sqj[n] - 2.0f * g, 1e-11f));
          if (vi & (njv[n] < nc) & (mi != njv[n]))
            lsum += fmaxf(1.0f + dist - ndi, 0.0f);     // nd=inf -> 0 automatically
        }
      }
    }
    #pragma unroll
    for (int o = 32; o; o >>= 1) lsum += __shfl_xor(lsum, o);
    if (lane == 0) red[wid] = lsum;
    __syncthreads();
    if (tid == 0) atomicAdd(accf, red[0] + red[1] + red[2] + red[3]);
  }
  // pair-count (half 0 only) + last-block finalize (atomics only)
  if (tid == 0) {
    int* cnt  = (int*)accf + 1;
    int* done = (int*)accf + 2;
    if (half == 0 && nc < NN) atomicAdd(cnt, nc * (nc - 1));
    __threadfence();
    if (atomicAdd(done, 1) == 2 * NC - 1) {
      const float tot = atomicAdd(accf, 0.0f);    // atomic read
      const int n = atomicAdd(cnt, 0);            // atomic read
      out[0] = tot / (float)n;
    }
  }
}

extern "C" void kernel_launch(void* const* d_in, const int* in_sizes, int n_in,
                              void* d_out, int out_size, void* d_ws, size_t ws_size,
                              hipStream_t stream) {
  const float* F = (const float*)d_in[0];
  const int* labels = (const int*)d_in[1];   // harness materializes integers as int32
  const float* negu = (const float*)d_in[2];
  char* ws = (char*)d_ws;
  u16*   Fb    = (u16*)(ws + FB_OFF);
  float* sq    = (float*)(ws + SQ_OFF);
  float* accf  = (float*)(ws + ACC_OFF);
  int*   cc    = (int*)(ws + CC_OFF);
  int*   pos   = (int*)(ws + POS_OFF);

  k_pc <<<2048 + NC, 256, 0, stream>>>(F, labels, Fb, sq, cc, pos, (int*)accf);
  k_cls<<<2 * NC,    256, 0, stream>>>(Fb, sq, negu, cc, pos, accf, (float*)d_out);
}